// Round 3
// baseline (764.311 us; speedup 1.0000x reference)
//
#include <hip/hip_runtime.h>
#include <hip/hip_bf16.h>
#include <math.h>

// B=16,S=1024 -> M=16384 tokens; D=1024, F=4096, E=8, R=32, SCALING=0.5
// Big GEMMs: 256x256 tile, BK=64, 8 waves, 4-phase/K-tile counted-vmcnt
// schedule. All GEMM operands live in a PACKED layout: each 256-row x
// 32-col half-tile is a contiguous 16KB block; within a block
// short_off(r,c) = r*32 + (c ^ ((r&8)<<1))  (st-swizzle for conflict-free
// ds_read_b128). Staging is a verbatim 16KB copy (contiguous 1KiB per
// global_load_lds instruction). LoRA-B folded into K as extension columns:
// GEMM1 [M,1280]x[4096,1280]^T, GEMM2 [M,4352]x[1024,4352]^T.

#define M_TOK 16384
#define DIM_D 1024
#define DIM_F 4096
#define NEXP 8
#define RANK 32
#define NER 256   // NEXP*RANK
#define K1 1280   // DIM_D + NER
#define K2 4352   // DIM_F + NER

typedef __attribute__((ext_vector_type(8))) short bf16x8;
typedef __attribute__((ext_vector_type(4))) short sh4;
typedef __attribute__((ext_vector_type(4))) float f32x4;

__device__ inline short f2bs(float x) {
  __hip_bfloat16 h = __float2bfloat16(x);
  return *reinterpret_cast<short*>(&h);
}

__device__ inline void async16(const void* g, void* l) {
  __builtin_amdgcn_global_load_lds(
      (__attribute__((address_space(1))) void*)(g),
      (__attribute__((address_space(3))) void*)(l), 16, 0, 0);
}

// packed-layout helpers: blk = half-tile index, off = swizzled in-block offset
// packed element (row, k) of a [rows, KP] matrix:
//   blk  = (row>>8)*(KP>>5) + (k>>5)
//   off  = (row&255)*32 + ((k&31) ^ ((row&8)<<1))        [shorts]
__device__ inline size_t pk_blk(int row, int k, int KP) {
  return (size_t)(row >> 8) * (KP >> 5) + (k >> 5);
}
__device__ inline int pk_off(int row, int k) {
  return (row & 255) * 32 + ((k & 31) ^ ((row & 8) << 1));
}

// ---------- fp32 [rows,C] -> packed bf16 (KP-pitch), 8 cols/thread ----------
__global__ __launch_bounds__(256) void convert_packed(
    const float* __restrict__ in, short* __restrict__ out,
    int c8, int KP, int n8)
{
  const int i = blockIdx.x * 256 + threadIdx.x;
  if (i >= n8) return;
  const int row = i / c8;
  const int k = (i % c8) * 8;
  const float4* p = (const float4*)(in + (size_t)row * (c8 * 8) + k);
  float4 u = p[0], v = p[1];
  bf16x8 r;
  r[0] = f2bs(u.x); r[1] = f2bs(u.y); r[2] = f2bs(u.z); r[3] = f2bs(u.w);
  r[4] = f2bs(v.x); r[5] = f2bs(v.y); r[6] = f2bs(v.z); r[7] = f2bs(v.w);
  *(bf16x8*)(out + pk_blk(row, k, KP) * 8192 + pk_off(row, k)) = r;
}

// ---------- LoRA-B [E,Nn,R] fp32 -> packed bf16 at k = ooff+e*32 ----------
__global__ __launch_bounds__(256) void pack_lorab(
    const float* __restrict__ in, short* __restrict__ out,
    int Nn, int KP, int ooff, int n8)
{
  const int i = blockIdx.x * 256 + threadIdx.x;
  if (i >= n8) return;
  const int e = i / (Nn * 4);
  const int rem = i % (Nn * 4);
  const int n = rem >> 2;
  const int r8 = (rem & 3) * 8;
  const int k = ooff + e * RANK + r8;
  const float4* p = (const float4*)(in + ((size_t)e * Nn + n) * RANK + r8);
  float4 u = p[0], v = p[1];
  bf16x8 r;
  r[0] = f2bs(u.x); r[1] = f2bs(u.y); r[2] = f2bs(u.z); r[3] = f2bs(u.w);
  r[4] = f2bs(v.x); r[5] = f2bs(v.y); r[6] = f2bs(v.z); r[7] = f2bs(v.w);
  *(bf16x8*)(out + pk_blk(n, k, KP) * 8192 + pk_off(n, k)) = r;
}

// ---------- router (one wave per token) + fused x->bf16 into packed xbw ----
__global__ __launch_bounds__(256) void router_kernel(
    const float* __restrict__ X,     // [M, D]
    const float* __restrict__ RW,    // [E, D]
    const float* __restrict__ RB,    // [E]
    float* __restrict__ routing_out, // [M, E]
    float* __restrict__ ec_out,      // [M, E]
    int* __restrict__ idx_out,       // [M]
    short* __restrict__ XB)          // packed [M, K1] bf16, cols 0..1023
{
  const int wave = threadIdx.x >> 6;
  const int lane = threadIdx.x & 63;
  const int t = blockIdx.x * 4 + wave;

  const float4* xp = (const float4*)(X + (size_t)t * DIM_D);
  float4 xv[4];
#pragma unroll
  for (int i = 0; i < 4; ++i) xv[i] = xp[lane + 64 * i];

  // fused bf16 conversion of x into packed A buffer (4-short runs stay
  // contiguous under the 16-short XOR since k0 is 4-aligned within 16)
#pragma unroll
  for (int i = 0; i < 4; ++i) {
    sh4 o;
    o[0] = f2bs(xv[i].x); o[1] = f2bs(xv[i].y);
    o[2] = f2bs(xv[i].z); o[3] = f2bs(xv[i].w);
    const int k0 = (lane + 64 * i) * 4;
    *(sh4*)&XB[pk_blk(t, k0, K1) * 8192 + pk_off(t, k0)] = o;
  }

  float logit[NEXP];
#pragma unroll
  for (int e = 0; e < NEXP; ++e) {
    const float4* wp = (const float4*)(RW + (size_t)e * DIM_D);
    double p = 0.0;
#pragma unroll
    for (int i = 0; i < 4; ++i) {
      float4 w = wp[lane + 64 * i];
      p += (double)xv[i].x * w.x + (double)xv[i].y * w.y +
           (double)xv[i].z * w.z + (double)xv[i].w * w.w;
    }
#pragma unroll
    for (int off = 32; off > 0; off >>= 1) p += __shfl_xor(p, off);
    logit[e] = (float)p + RB[e];
  }
  float m = logit[0];
  int am = 0;
#pragma unroll
  for (int e = 1; e < NEXP; ++e)
    if (logit[e] > m) { m = logit[e]; am = e; }
  float pr[NEXP], s = 0.f;
#pragma unroll
  for (int e = 0; e < NEXP; ++e) { pr[e] = expf(logit[e] - m); s += pr[e]; }
  const float inv = 1.f / s;
  if (lane < NEXP) {
    float r = pr[lane] * inv;
    routing_out[(size_t)t * NEXP + lane] = r;
    float y = (lane == am) ? 1.f : 0.f;
    ec_out[(size_t)t * NEXP + lane] = (y - r) + r;
  }
  if (lane == 0) idx_out[t] = am;
}

// ---------- LoRA-A GEMM (N=256), 128x128 tile, packed in/out ----------
// out packed col (OOFF+gc) = bf16( gc>>5==idx[t] ? 0.5*(acc + A_b[gc]) : 0 )
template <int KM, int LDA, int OPK, int OOFF>
__global__ __launch_bounds__(256, 2) void lora_a_gemm(
    const short* __restrict__ A, const short* __restrict__ Bm,
    const float* __restrict__ bias, const int* __restrict__ idx,
    short* __restrict__ out)
{
  __shared__ __align__(16) short As[128 * 32];
  __shared__ __align__(16) short Bs[128 * 32];

  const int tid = threadIdx.x;
  const int m0 = blockIdx.y * 128;
  const int n0 = blockIdx.x * 128;
  const int lane = tid & 63;
  const int wv = tid >> 6;
  const int quad = lane >> 4;
  const int lrow = lane & 15;
  const int wr = wv >> 1;
  const int wc = wv & 1;
  const int swz = (quad * 8) ^ ((lrow & 8) << 1);

  f32x4 acc[4][4];
#pragma unroll
  for (int i = 0; i < 4; ++i)
#pragma unroll
    for (int j = 0; j < 4; ++j) acc[i][j] = (f32x4){0.f, 0.f, 0.f, 0.f};

  const short* Ab = A + ((size_t)(m0 >> 8) * (LDA >> 5)) * 8192 +
                    (size_t)(m0 & 255) * 32;
  const short* Bb = Bm + ((size_t)(n0 >> 8) * (KM >> 5)) * 8192 +
                    (size_t)(n0 & 255) * 32;

  for (int it = 0; it < KM / 32; ++it) {
    const short* a0 = Ab + (size_t)it * 8192 + tid * 8;
    const short* b0 = Bb + (size_t)it * 8192 + tid * 8;
    async16(a0, &As[tid * 8]);
    async16(a0 + 2048, &As[tid * 8 + 2048]);
    async16(b0, &Bs[tid * 8]);
    async16(b0 + 2048, &Bs[tid * 8 + 2048]);
    __syncthreads();

    bf16x8 af[4], bfv[4];
#pragma unroll
    for (int i = 0; i < 4; ++i)
      af[i] = *(const bf16x8*)&As[(wr * 64 + i * 16 + lrow) * 32 + swz];
#pragma unroll
    for (int j = 0; j < 4; ++j)
      bfv[j] = *(const bf16x8*)&Bs[(wc * 64 + j * 16 + lrow) * 32 + swz];
#pragma unroll
    for (int i = 0; i < 4; ++i)
#pragma unroll
      for (int j = 0; j < 4; ++j)
        acc[i][j] = __builtin_amdgcn_mfma_f32_16x16x32_bf16(af[i], bfv[j],
                                                            acc[i][j], 0, 0, 0);
    __syncthreads();
  }

  float cb[4];
#pragma unroll
  for (int j = 0; j < 4; ++j) cb[j] = bias[n0 + wc * 64 + j * 16 + lrow];

#pragma unroll
  for (int i = 0; i < 4; ++i) {
#pragma unroll
    for (int reg = 0; reg < 4; ++reg) {
      const int t = m0 + wr * 64 + i * 16 + quad * 4 + reg;
      const int e = idx[t];
#pragma unroll
      for (int j = 0; j < 4; ++j) {
        const int gc = n0 + wc * 64 + j * 16 + lrow;
        float v = ((gc >> 5) == e) ? 0.5f * (acc[i][j][reg] + cb[j]) : 0.f;
        const int k = OOFF + gc;
        out[pk_blk(t, k, OPK) * 8192 + pk_off(t, k)] = f2bs(v);
      }
    }
  }
}

// ---------- 256x256 4-phase/K-tile GEMM, C = A[M,K] * Bm[N,K]^T ----------
// Packed operands; staging = verbatim 16KB half-tile copies (1KiB/instr).
// Front-loaded prefetch: all 4 halves of tile t+1 issued in P1-P2;
// drains vmcnt(8)@P2 (covers this tile's ks1) and vmcnt(4)@P4 (covers
// next tile's ks0) - 3-4 phases of latency cover, 12-deep queue.
// EPI: 1 = gelu(acc+bias+0.5*LB[e]) -> packed bf16 (KP=POUT)
//      0 = acc+bias+0.5*LB[e]       -> fp32 row-major pitch POUT
template <int K, int N, int POUT, int EPI>
__global__ __launch_bounds__(512, 2) void gemm256(
    const short* __restrict__ A, const short* __restrict__ Bm,
    const float* __restrict__ LB, const float* __restrict__ bias,
    const int* __restrict__ idx, void* __restrict__ outv)
{
  static_assert(K % 128 == 0, "K must be multiple of 128");
  __shared__ __align__(16) short lds[65536];  // 2 buf x (A 16K + B 16K) shorts

  const int tid = threadIdx.x;
  const int lane = tid & 63;
  const int wv = tid >> 6;
  const int wr = wv >> 2;   // 0..1
  const int wc = wv & 3;    // 0..3
  const int quad = lane >> 4;
  const int lrow = lane & 15;

  // T1: XCD swizzle (nwg % 8 == 0 for both grids), row-major over N
  const int gx = gridDim.x;
  int id = blockIdx.y * gx + blockIdx.x;
  const int nwg = gx * gridDim.y;
  id = (id & 7) * (nwg >> 3) + (id >> 3);
  const int m0 = (id / gx) * 256;
  const int n0 = (id % gx) * 256;

  const short* Abase = A + (size_t)(m0 >> 8) * (K >> 5) * 8192;
  const short* Bbase = Bm + (size_t)(n0 >> 8) * (K >> 5) * 8192;

  // swizzled read offsets (shorts): row*32 + (quad*8 ^ ((lrow&8)<<1))
  const int swz = (quad * 8) ^ ((lrow & 8) << 1);
  const int arowb = wr * 4096 + lrow * 32 + swz;          // A: + mh*2048 + i*512
  const int browb = 16384 + wc * 2048 + lrow * 32 + swz;  // B: + j*512

  f32x4 acc[8][4];
#pragma unroll
  for (int i = 0; i < 8; ++i)
#pragma unroll
    for (int j = 0; j < 4; ++j) acc[i][j] = (f32x4){0.f, 0.f, 0.f, 0.f};

  bf16x8 af[4], bfv[4];

#define STG(base, t, h, tens, buf)                                            \
  {                                                                           \
    const short* s_ = (base) + (size_t)(2 * (t) + (h)) * 8192 + tid * 8;      \
    short* d_ = &lds[(buf)*32768 + (tens) + (h)*8192 + tid * 8];              \
    async16(s_, d_);                                                          \
    async16(s_ + 4096, d_ + 4096);                                            \
  }
#define RDB(h, buf)                                                           \
  _Pragma("unroll") for (int j = 0; j < 4; ++j)                               \
      bfv[j] = *(const bf16x8*)&lds[(buf)*32768 + (h)*8192 + browb + j * 512];
#define RDA(mh, h, buf)                                                       \
  _Pragma("unroll") for (int i = 0; i < 4; ++i)                               \
      af[i] = *(const bf16x8*)&lds[(buf)*32768 + (h)*8192 + arowb +           \
                                   (mh)*2048 + i * 512];
#define MM(mh)                                                                \
  {                                                                           \
    __builtin_amdgcn_s_setprio(1);                                            \
    _Pragma("unroll") for (int i = 0; i < 4; ++i)                             \
    _Pragma("unroll") for (int j = 0; j < 4; ++j)                             \
        acc[(mh)*4 + i][j] = __builtin_amdgcn_mfma_f32_16x16x32_bf16(         \
            af[i], bfv[j], acc[(mh)*4 + i][j], 0, 0, 0);                      \
    __builtin_amdgcn_s_setprio(0);                                            \
  }
#define BARR __builtin_amdgcn_s_barrier()
#define WV8 asm volatile("s_waitcnt vmcnt(8)" ::: "memory")
#define WV4 asm volatile("s_waitcnt vmcnt(4)" ::: "memory")
#define WV0 asm volatile("s_waitcnt vmcnt(0)" ::: "memory")
// one tile: compute buf b, stage tile t+1 into buf nb (b, nb literals)
#define TILE(t, b, nb)                                                        \
  STG(Abase, (t) + 1, 0, 0, nb);                                              \
  STG(Bbase, (t) + 1, 0, 16384, nb);                                          \
  RDB(0, b); RDA(0, 0, b); BARR; MM(0); BARR;                                 \
  STG(Abase, (t) + 1, 1, 0, nb);                                              \
  STG(Bbase, (t) + 1, 1, 16384, nb);                                          \
  RDA(1, 0, b); BARR; MM(1); WV8; BARR;                                       \
  RDB(1, b); RDA(0, 1, b); BARR; MM(0); BARR;                                 \
  RDA(1, 1, b); BARR; MM(1); WV4; BARR;

  // prologue: stage tile 0 fully into buf 0; ks0 must land, ks1 may fly
  STG(Abase, 0, 0, 0, 0);
  STG(Bbase, 0, 0, 16384, 0);
  STG(Abase, 0, 1, 0, 0);
  STG(Bbase, 0, 1, 16384, 0);
  WV4; BARR;

  constexpr int NT = K / 64;  // even (20 or 68)
  for (int p = 0; p < NT / 2 - 1; ++p) {
    const int t0 = 2 * p;
    TILE(t0, 0, 1);
    TILE(t0 + 1, 1, 0);
  }
  TILE(NT - 2, 0, 1);
  {  // last tile (buf 1), no staging
    RDB(0, 1); RDA(0, 0, 1); BARR; MM(0); BARR;
    RDA(1, 0, 1);            BARR; MM(1); WV0; BARR;
    RDB(1, 1); RDA(0, 1, 1); BARR; MM(0); BARR;
    RDA(1, 1, 1);                  MM(1);
  }
#undef STG
#undef RDB
#undef RDA
#undef MM
#undef BARR
#undef WV8
#undef WV4
#undef WV0
#undef TILE

  // epilogue: C row = quad*4+reg, col = lrow (dtype-independent C/D map)
  const int orow0 = m0 + wr * 128;
  const int ocol0 = n0 + wc * 64;
  float cb[4];
#pragma unroll
  for (int j = 0; j < 4; ++j) cb[j] = bias[ocol0 + j * 16 + lrow];

#pragma unroll
  for (int i = 0; i < 8; ++i) {
#pragma unroll
    for (int reg = 0; reg < 4; ++reg) {
      const int t = orow0 + i * 16 + quad * 4 + reg;
      const int e = idx[t];
      const float* lbp = LB + (size_t)e * N;
#pragma unroll
      for (int j = 0; j < 4; ++j) {
        const int gc = ocol0 + j * 16 + lrow;
        float v = acc[i][j][reg] + cb[j] + 0.5f * lbp[gc];
        if (EPI == 1) {
          v = 0.5f * v * (1.0f + erff(v * 0.70710678118654752f));
          ((short*)outv)[pk_blk(t, gc, POUT) * 8192 + pk_off(t, gc)] = f2bs(v);
        } else {
          ((float*)outv)[(size_t)t * POUT + gc] = v;
        }
      }
    }
  }
}

extern "C" void kernel_launch(void* const* d_in, const int* in_sizes, int n_in,
                              void* d_out, int out_size, void* d_ws, size_t ws_size,
                              hipStream_t stream) {
  (void)in_sizes; (void)n_in; (void)out_size; (void)ws_size;
  const float* x        = (const float*)d_in[0];
  const float* router_w = (const float*)d_in[1];
  const float* router_b = (const float*)d_in[2];
  const float* fc1_w    = (const float*)d_in[3];
  const float* fc1_b    = (const float*)d_in[4];
  const float* fc2_w    = (const float*)d_in[5];
  const float* fc2_b    = (const float*)d_in[6];
  const float* down_A_w = (const float*)d_in[7];   // [E,R,D]
  const float* down_A_b = (const float*)d_in[8];   // [E*R]
  const float* down_B_w = (const float*)d_in[9];   // [E,F,R]
  const float* down_B_b = (const float*)d_in[10];  // [E,F]
  const float* up_A_w   = (const float*)d_in[11];  // [E,R,F]
  const float* up_A_b   = (const float*)d_in[12];  // [E*R]
  const float* up_B_w   = (const float*)d_in[13];  // [E,D,R]
  const float* up_B_b   = (const float*)d_in[14];  // [E,D]

  // ws: idx | xbw pk[M,K1] | aw pk[M,K2] | B1w pk[F,K1] | B2w pk[D,K2] | dAb | uAb
  char* ws = (char*)d_ws;
  size_t off = 0;
  int* idxp  = (int*)ws;              off += (size_t)M_TOK * 4;
  short* xbw = (short*)(ws + off);    off += (size_t)M_TOK * K1 * 2;
  short* aw  = (short*)(ws + off);    off += (size_t)M_TOK * K2 * 2;
  short* B1w = (short*)(ws + off);    off += (size_t)DIM_F * K1 * 2;
  short* B2w = (short*)(ws + off);    off += (size_t)DIM_D * K2 * 2;
  short* dAb = (short*)(ws + off);    off += (size_t)NER * DIM_D * 2;
  short* uAb = (short*)(ws + off);    off += (size_t)NER * DIM_F * 2;

  float* out = (float*)d_out;
  float* routing = out + (size_t)M_TOK * DIM_D;
  float* ec = routing + (size_t)M_TOK * NEXP;

  // weight conversions / packing into packed-tile layouts
  convert_packed<<<2048, 256, 0, stream>>>(fc1_w, B1w, 128, K1, 524288);
  convert_packed<<<2048, 256, 0, stream>>>(fc2_w, B2w, 512, K2, 524288);
  convert_packed<<<128,  256, 0, stream>>>(down_A_w, dAb, 128, DIM_D, 32768);
  convert_packed<<<512,  256, 0, stream>>>(up_A_w,   uAb, 512, DIM_F, 131072);
  pack_lorab<<<512, 256, 0, stream>>>(down_B_w, B1w, DIM_F, K1, DIM_D, 131072);
  pack_lorab<<<128, 256, 0, stream>>>(up_B_w,   B2w, DIM_D, K2, DIM_F, 32768);

  // router (+ x -> packed bf16 into xbw cols 0..1023)
  router_kernel<<<M_TOK / 4, 256, 0, stream>>>(x, router_w, router_b, routing,
                                               ec, idxp, xbw);
  // LoRA-A down: xbw packed cols 1024..1279 = mask(0.5*(x.dA^T + b))
  lora_a_gemm<DIM_D, K1, K1, DIM_D>
      <<<dim3(2, M_TOK / 128), 256, 0, stream>>>(xbw, dAb, down_A_b, idxp, xbw);
  // GEMM1: aw packed cols 0..4095 = gelu(xbw . B1w^T + fc1_b + 0.5*dB_b[e])
  gemm256<K1, DIM_F, K2, 1>
      <<<dim3(DIM_F / 256, M_TOK / 256), 512, 0, stream>>>(
          xbw, B1w, down_B_b, fc1_b, idxp, aw);
  // LoRA-A up: aw packed cols 4096..4351 = mask(0.5*(a.uA^T + b))
  lora_a_gemm<DIM_F, K2, K2, DIM_F>
      <<<dim3(2, M_TOK / 128), 256, 0, stream>>>(aw, uAb, up_A_b, idxp, aw);
  // GEMM2: out = aw . B2w^T + fc2_b + 0.5*uB_b[e]  (fp32 row-major)
  gemm256<K2, DIM_D, DIM_D, 0>
      <<<dim3(DIM_D / 256, M_TOK / 256), 512, 0, stream>>>(
          aw, B2w, up_B_b, fc2_b, idxp, out);
}

// Round 4
// 660.851 us; speedup vs baseline: 1.1566x; 1.1566x over previous
//
#include <hip/hip_runtime.h>
#include <hip/hip_bf16.h>
#include <math.h>

// B=16,S=1024 -> M=16384 tokens; D=1024, F=4096, E=8, R=32, SCALING=0.5
// Big GEMMs: 256x256 tile, BK=64, 8 waves. PACKED operand layout: each
// 256-row x 32-col half-tile is a contiguous 16KB block with the bank
// swizzle baked in: short_off(r,c) = r*32 + (c ^ ((r&8)<<1)). Staging is a
// verbatim contiguous copy (1KiB per global_load_lds instruction - no
// scatter). K-loop schedule = R1's proven skeleton: per phase {ds_reads;
// one 16KB half stage; asm s_barrier; MFMA(setprio)}, counted vmcnt(4)
// at phases 2 and 4 of each 64-K window (never 0 mid-loop).
// LoRA-B folded into K: GEMM1 [M,1280]x[4096,1280]^T, GEMM2 [M,4352]x[1024,4352]^T.

#define M_TOK 16384
#define DIM_D 1024
#define DIM_F 4096
#define NEXP 8
#define RANK 32
#define NER 256   // NEXP*RANK
#define K1 1280   // DIM_D + NER
#define K2 4352   // DIM_F + NER

typedef __attribute__((ext_vector_type(8))) short bf16x8;
typedef __attribute__((ext_vector_type(4))) short sh4;
typedef __attribute__((ext_vector_type(4))) float f32x4;

__device__ inline short f2bs(float x) {
  __hip_bfloat16 h = __float2bfloat16(x);
  return *reinterpret_cast<short*>(&h);
}

__device__ inline void async16(const void* g, void* l) {
  __builtin_amdgcn_global_load_lds(
      (__attribute__((address_space(1))) void*)(g),
      (__attribute__((address_space(3))) void*)(l), 16, 0, 0);
}

// packed-layout helpers: blk = half-tile index, off = swizzled in-block offset
// packed element (row, k) of a [rows, KP] matrix:
//   blk  = (row>>8)*(KP>>5) + (k>>5)
//   off  = (row&255)*32 + ((k&31) ^ ((row&8)<<1))        [shorts]
__device__ inline size_t pk_blk(int row, int k, int KP) {
  return (size_t)(row >> 8) * (KP >> 5) + (k >> 5);
}
__device__ inline int pk_off(int row, int k) {
  return (row & 255) * 32 + ((k & 31) ^ ((row & 8) << 1));
}

// ---------- fp32 [rows,C] -> packed bf16 (KP-pitch), 8 cols/thread ----------
__global__ __launch_bounds__(256) void convert_packed(
    const float* __restrict__ in, short* __restrict__ out,
    int c8, int KP, int n8)
{
  const int i = blockIdx.x * 256 + threadIdx.x;
  if (i >= n8) return;
  const int row = i / c8;
  const int k = (i % c8) * 8;
  const float4* p = (const float4*)(in + (size_t)row * (c8 * 8) + k);
  float4 u = p[0], v = p[1];
  bf16x8 r;
  r[0] = f2bs(u.x); r[1] = f2bs(u.y); r[2] = f2bs(u.z); r[3] = f2bs(u.w);
  r[4] = f2bs(v.x); r[5] = f2bs(v.y); r[6] = f2bs(v.z); r[7] = f2bs(v.w);
  *(bf16x8*)(out + pk_blk(row, k, KP) * 8192 + pk_off(row, k)) = r;
}

// ---------- LoRA-B [E,Nn,R] fp32 -> packed bf16 at k = ooff+e*32 ----------
__global__ __launch_bounds__(256) void pack_lorab(
    const float* __restrict__ in, short* __restrict__ out,
    int Nn, int KP, int ooff, int n8)
{
  const int i = blockIdx.x * 256 + threadIdx.x;
  if (i >= n8) return;
  const int e = i / (Nn * 4);
  const int rem = i % (Nn * 4);
  const int n = rem >> 2;
  const int r8 = (rem & 3) * 8;
  const int k = ooff + e * RANK + r8;
  const float4* p = (const float4*)(in + ((size_t)e * Nn + n) * RANK + r8);
  float4 u = p[0], v = p[1];
  bf16x8 r;
  r[0] = f2bs(u.x); r[1] = f2bs(u.y); r[2] = f2bs(u.z); r[3] = f2bs(u.w);
  r[4] = f2bs(v.x); r[5] = f2bs(v.y); r[6] = f2bs(v.z); r[7] = f2bs(v.w);
  *(bf16x8*)(out + pk_blk(n, k, KP) * 8192 + pk_off(n, k)) = r;
}

// ---------- router (one wave per token) + fused x->bf16 into packed xbw ----
__global__ __launch_bounds__(256) void router_kernel(
    const float* __restrict__ X,     // [M, D]
    const float* __restrict__ RW,    // [E, D]
    const float* __restrict__ RB,    // [E]
    float* __restrict__ routing_out, // [M, E]
    float* __restrict__ ec_out,      // [M, E]
    int* __restrict__ idx_out,       // [M]
    short* __restrict__ XB)          // packed [M, K1] bf16, cols 0..1023
{
  const int wave = threadIdx.x >> 6;
  const int lane = threadIdx.x & 63;
  const int t = blockIdx.x * 4 + wave;

  const float4* xp = (const float4*)(X + (size_t)t * DIM_D);
  float4 xv[4];
#pragma unroll
  for (int i = 0; i < 4; ++i) xv[i] = xp[lane + 64 * i];

  // fused bf16 conversion of x into packed A buffer (4-short runs stay
  // contiguous under the 16-short XOR since k0 is 4-aligned within 16)
#pragma unroll
  for (int i = 0; i < 4; ++i) {
    sh4 o;
    o[0] = f2bs(xv[i].x); o[1] = f2bs(xv[i].y);
    o[2] = f2bs(xv[i].z); o[3] = f2bs(xv[i].w);
    const int k0 = (lane + 64 * i) * 4;
    *(sh4*)&XB[pk_blk(t, k0, K1) * 8192 + pk_off(t, k0)] = o;
  }

  float logit[NEXP];
#pragma unroll
  for (int e = 0; e < NEXP; ++e) {
    const float4* wp = (const float4*)(RW + (size_t)e * DIM_D);
    double p = 0.0;
#pragma unroll
    for (int i = 0; i < 4; ++i) {
      float4 w = wp[lane + 64 * i];
      p += (double)xv[i].x * w.x + (double)xv[i].y * w.y +
           (double)xv[i].z * w.z + (double)xv[i].w * w.w;
    }
#pragma unroll
    for (int off = 32; off > 0; off >>= 1) p += __shfl_xor(p, off);
    logit[e] = (float)p + RB[e];
  }
  float m = logit[0];
  int am = 0;
#pragma unroll
  for (int e = 1; e < NEXP; ++e)
    if (logit[e] > m) { m = logit[e]; am = e; }
  float pr[NEXP], s = 0.f;
#pragma unroll
  for (int e = 0; e < NEXP; ++e) { pr[e] = expf(logit[e] - m); s += pr[e]; }
  const float inv = 1.f / s;
  if (lane < NEXP) {
    float r = pr[lane] * inv;
    routing_out[(size_t)t * NEXP + lane] = r;
    float y = (lane == am) ? 1.f : 0.f;
    ec_out[(size_t)t * NEXP + lane] = (y - r) + r;
  }
  if (lane == 0) idx_out[t] = am;
}

// ---------- LoRA-A GEMM (N=256), 128x128 tile, packed in/out ----------
// out packed col (OOFF+gc) = bf16( gc>>5==idx[t] ? 0.5*(acc + A_b[gc]) : 0 )
template <int KM, int LDA, int OPK, int OOFF>
__global__ __launch_bounds__(256, 2) void lora_a_gemm(
    const short* __restrict__ A, const short* __restrict__ Bm,
    const float* __restrict__ bias, const int* __restrict__ idx,
    short* __restrict__ out)
{
  __shared__ __align__(16) short As[128 * 32];
  __shared__ __align__(16) short Bs[128 * 32];

  const int tid = threadIdx.x;
  const int m0 = blockIdx.y * 128;
  const int n0 = blockIdx.x * 128;
  const int lane = tid & 63;
  const int wv = tid >> 6;
  const int quad = lane >> 4;
  const int lrow = lane & 15;
  const int wr = wv >> 1;
  const int wc = wv & 1;
  const int swz = (quad * 8) ^ ((lrow & 8) << 1);

  f32x4 acc[4][4];
#pragma unroll
  for (int i = 0; i < 4; ++i)
#pragma unroll
    for (int j = 0; j < 4; ++j) acc[i][j] = (f32x4){0.f, 0.f, 0.f, 0.f};

  const short* Ab = A + ((size_t)(m0 >> 8) * (LDA >> 5)) * 8192 +
                    (size_t)(m0 & 255) * 32;
  const short* Bb = Bm + ((size_t)(n0 >> 8) * (KM >> 5)) * 8192 +
                    (size_t)(n0 & 255) * 32;

  for (int it = 0; it < KM / 32; ++it) {
    const short* a0 = Ab + (size_t)it * 8192 + tid * 8;
    const short* b0 = Bb + (size_t)it * 8192 + tid * 8;
    async16(a0, &As[tid * 8]);
    async16(a0 + 2048, &As[tid * 8 + 2048]);
    async16(b0, &Bs[tid * 8]);
    async16(b0 + 2048, &Bs[tid * 8 + 2048]);
    __syncthreads();

    bf16x8 af[4], bfv[4];
#pragma unroll
    for (int i = 0; i < 4; ++i)
      af[i] = *(const bf16x8*)&As[(wr * 64 + i * 16 + lrow) * 32 + swz];
#pragma unroll
    for (int j = 0; j < 4; ++j)
      bfv[j] = *(const bf16x8*)&Bs[(wc * 64 + j * 16 + lrow) * 32 + swz];
#pragma unroll
    for (int i = 0; i < 4; ++i)
#pragma unroll
      for (int j = 0; j < 4; ++j)
        acc[i][j] = __builtin_amdgcn_mfma_f32_16x16x32_bf16(af[i], bfv[j],
                                                            acc[i][j], 0, 0, 0);
    __syncthreads();
  }

  float cb[4];
#pragma unroll
  for (int j = 0; j < 4; ++j) cb[j] = bias[n0 + wc * 64 + j * 16 + lrow];

#pragma unroll
  for (int i = 0; i < 4; ++i) {
#pragma unroll
    for (int reg = 0; reg < 4; ++reg) {
      const int t = m0 + wr * 64 + i * 16 + quad * 4 + reg;
      const int e = idx[t];
#pragma unroll
      for (int j = 0; j < 4; ++j) {
        const int gc = n0 + wc * 64 + j * 16 + lrow;
        float v = ((gc >> 5) == e) ? 0.5f * (acc[i][j][reg] + cb[j]) : 0.f;
        const int k = OOFF + gc;
        out[pk_blk(t, k, OPK) * 8192 + pk_off(t, k)] = f2bs(v);
      }
    }
  }
}

// ---------- 256x256 GEMM, C = A[M,K] * Bm[N,K]^T ----------
// Packed operands; staging = contiguous 16KB half-tile copies (1KiB/instr).
// R1 schedule: per 64-K window 4 phases {reads; one half staged; BARR;
// MFMA; BARR}, vmcnt(4) at ends of phases 2 and 4. Raw-asm barriers.
// EPI: 1 = gelu(acc+bias+0.5*LB[e]) -> packed bf16 (KP=POUT)
//      0 = acc+bias+0.5*LB[e]       -> fp32 row-major pitch POUT
template <int K, int N, int POUT, int EPI>
__global__ __launch_bounds__(512, 2) void gemm256(
    const short* __restrict__ A, const short* __restrict__ Bm,
    const float* __restrict__ LB, const float* __restrict__ bias,
    const int* __restrict__ idx, void* __restrict__ outv)
{
  static_assert(K % 128 == 0, "K must be multiple of 128");
  __shared__ __align__(16) short lds[65536];  // 2 buf x (A 16K + B 16K) shorts

  const int tid = threadIdx.x;
  const int lane = tid & 63;
  const int wv = tid >> 6;
  const int wr = wv >> 2;   // 0..1
  const int wc = wv & 3;    // 0..3
  const int quad = lane >> 4;
  const int lrow = lane & 15;

  // T1: XCD swizzle (nwg % 8 == 0 for both grids), row-major over N
  const int gx = gridDim.x;
  int id = blockIdx.y * gx + blockIdx.x;
  const int nwg = gx * gridDim.y;
  id = (id & 7) * (nwg >> 3) + (id >> 3);
  const int m0 = (id / gx) * 256;
  const int n0 = (id % gx) * 256;

  const short* Abase = A + (size_t)(m0 >> 8) * (K >> 5) * 8192;
  const short* Bbase = Bm + (size_t)(n0 >> 8) * (K >> 5) * 8192;

  // swizzled read offsets (shorts): row*32 + (quad*8 ^ ((lrow&8)<<1))
  const int swz = (quad * 8) ^ ((lrow & 8) << 1);
  const int arowb = wr * 4096 + lrow * 32 + swz;          // A: + mh*2048 + i*512
  const int browb = 16384 + wc * 2048 + lrow * 32 + swz;  // B: + j*512

  f32x4 acc[8][4];
#pragma unroll
  for (int i = 0; i < 8; ++i)
#pragma unroll
    for (int j = 0; j < 4; ++j) acc[i][j] = (f32x4){0.f, 0.f, 0.f, 0.f};

  bf16x8 af[4], bfv[4];

#define STG(base, t, h, tens, buf)                                            \
  {                                                                           \
    const short* s_ = (base) + (size_t)(2 * (t) + (h)) * 8192 + tid * 8;      \
    short* d_ = &lds[(buf)*32768 + (tens) + (h)*8192 + tid * 8];              \
    async16(s_, d_);                                                          \
    async16(s_ + 4096, d_ + 4096);                                            \
  }
#define RDB(h, buf)                                                           \
  _Pragma("unroll") for (int j = 0; j < 4; ++j)                               \
      bfv[j] = *(const bf16x8*)&lds[(buf)*32768 + (h)*8192 + browb + j * 512];
#define RDA(mh, h, buf)                                                       \
  _Pragma("unroll") for (int i = 0; i < 4; ++i)                               \
      af[i] = *(const bf16x8*)&lds[(buf)*32768 + (h)*8192 + arowb +           \
                                   (mh)*2048 + i * 512];
#define MM(mh)                                                                \
  {                                                                           \
    __builtin_amdgcn_s_setprio(1);                                            \
    _Pragma("unroll") for (int i = 0; i < 4; ++i)                             \
    _Pragma("unroll") for (int j = 0; j < 4; ++j)                             \
        acc[(mh)*4 + i][j] = __builtin_amdgcn_mfma_f32_16x16x32_bf16(         \
            af[i], bfv[j], acc[(mh)*4 + i][j], 0, 0, 0);                      \
    __builtin_amdgcn_s_setprio(0);                                            \
  }
#define BARR asm volatile("s_barrier" ::: "memory")
#define WV4 asm volatile("s_waitcnt vmcnt(4)" ::: "memory")
#define WV0 asm volatile("s_waitcnt vmcnt(0)" ::: "memory")
// one 64-K window: compute buf b (tile t), stage tile t+1 into buf nb.
// Ledger (verified): drain@P2 guarantees halves staged 2-3 phases earlier
// (prev window P3/P4 = this tile's h1) landed; drain@P4 guarantees this
// window's P1/P2 stages (next tile's h0) landed before next window P1.
#define TILE(t, b, nb)                                                        \
  RDB(0, b); RDA(0, 0, b); STG(Abase, (t) + 1, 0, 0, nb);                     \
  BARR; MM(0); BARR;                                                          \
  RDA(1, 0, b); STG(Bbase, (t) + 1, 0, 16384, nb);                            \
  BARR; MM(1); WV4; BARR;                                                     \
  RDB(1, b); RDA(0, 1, b); STG(Abase, (t) + 1, 1, 0, nb);                     \
  BARR; MM(0); BARR;                                                          \
  RDA(1, 1, b); STG(Bbase, (t) + 1, 1, 16384, nb);                            \
  BARR; MM(1); WV4; BARR;

  // prologue: stage tile 0 fully into buf 0; h0 must land, h1 may fly
  STG(Abase, 0, 0, 0, 0);
  STG(Bbase, 0, 0, 16384, 0);
  STG(Abase, 0, 1, 0, 0);
  STG(Bbase, 0, 1, 16384, 0);
  WV4; BARR;

  constexpr int NI = K / 128;  // 10 or 34
  for (int it = 0; it < NI - 1; ++it) {
    TILE(2 * it, 0, 1);
    TILE(2 * it + 1, 1, 0);
  }
  TILE(2 * NI - 2, 0, 1);  // stages last tile (2*NI-1) into buf1
  {  // last tile (buf 1), no staging; WV0 before its h1 reads
    RDB(0, 1); RDA(0, 0, 1); BARR; MM(0); BARR;
    RDA(1, 0, 1);            BARR; MM(1); WV0; BARR;
    RDB(1, 1); RDA(0, 1, 1); BARR; MM(0); BARR;
    RDA(1, 1, 1);                  MM(1);
  }
#undef STG
#undef RDB
#undef RDA
#undef MM
#undef BARR
#undef WV4
#undef WV0
#undef TILE

  // epilogue: C row = quad*4+reg, col = lrow (dtype-independent C/D map)
  const int orow0 = m0 + wr * 128;
  const int ocol0 = n0 + wc * 64;
  float cb[4];
#pragma unroll
  for (int j = 0; j < 4; ++j) cb[j] = bias[ocol0 + j * 16 + lrow];

#pragma unroll
  for (int i = 0; i < 8; ++i) {
#pragma unroll
    for (int reg = 0; reg < 4; ++reg) {
      const int t = orow0 + i * 16 + quad * 4 + reg;
      const int e = idx[t];
      const float* lbp = LB + (size_t)e * N;
#pragma unroll
      for (int j = 0; j < 4; ++j) {
        const int gc = ocol0 + j * 16 + lrow;
        float v = acc[i][j][reg] + cb[j] + 0.5f * lbp[gc];
        if (EPI == 1) {
          v = 0.5f * v * (1.0f + erff(v * 0.70710678118654752f));
          ((short*)outv)[pk_blk(t, gc, POUT) * 8192 + pk_off(t, gc)] = f2bs(v);
        } else {
          ((float*)outv)[(size_t)t * POUT + gc] = v;
        }
      }
    }
  }
}

extern "C" void kernel_launch(void* const* d_in, const int* in_sizes, int n_in,
                              void* d_out, int out_size, void* d_ws, size_t ws_size,
                              hipStream_t stream) {
  (void)in_sizes; (void)n_in; (void)out_size; (void)ws_size;
  const float* x        = (const float*)d_in[0];
  const float* router_w = (const float*)d_in[1];
  const float* router_b = (const float*)d_in[2];
  const float* fc1_w    = (const float*)d_in[3];
  const float* fc1_b    = (const float*)d_in[4];
  const float* fc2_w    = (const float*)d_in[5];
  const float* fc2_b    = (const float*)d_in[6];
  const float* down_A_w = (const float*)d_in[7];   // [E,R,D]
  const float* down_A_b = (const float*)d_in[8];   // [E*R]
  const float* down_B_w = (const float*)d_in[9];   // [E,F,R]
  const float* down_B_b = (const float*)d_in[10];  // [E,F]
  const float* up_A_w   = (const float*)d_in[11];  // [E,R,F]
  const float* up_A_b   = (const float*)d_in[12];  // [E*R]
  const float* up_B_w   = (const float*)d_in[13];  // [E,D,R]
  const float* up_B_b   = (const float*)d_in[14];  // [E,D]

  // ws: idx | xbw pk[M,K1] | aw pk[M,K2] | B1w pk[F,K1] | B2w pk[D,K2] | dAb | uAb
  char* ws = (char*)d_ws;
  size_t off = 0;
  int* idxp  = (int*)ws;              off += (size_t)M_TOK * 4;
  short* xbw = (short*)(ws + off);    off += (size_t)M_TOK * K1 * 2;
  short* aw  = (short*)(ws + off);    off += (size_t)M_TOK * K2 * 2;
  short* B1w = (short*)(ws + off);    off += (size_t)DIM_F * K1 * 2;
  short* B2w = (short*)(ws + off);    off += (size_t)DIM_D * K2 * 2;
  short* dAb = (short*)(ws + off);    off += (size_t)NER * DIM_D * 2;
  short* uAb = (short*)(ws + off);    off += (size_t)NER * DIM_F * 2;

  float* out = (float*)d_out;
  float* routing = out + (size_t)M_TOK * DIM_D;
  float* ec = routing + (size_t)M_TOK * NEXP;

  // weight conversions / packing into packed-tile layouts
  convert_packed<<<2048, 256, 0, stream>>>(fc1_w, B1w, 128, K1, 524288);
  convert_packed<<<2048, 256, 0, stream>>>(fc2_w, B2w, 512, K2, 524288);
  convert_packed<<<128,  256, 0, stream>>>(down_A_w, dAb, 128, DIM_D, 32768);
  convert_packed<<<512,  256, 0, stream>>>(up_A_w,   uAb, 512, DIM_F, 131072);
  pack_lorab<<<512, 256, 0, stream>>>(down_B_w, B1w, DIM_F, K1, DIM_D, 131072);
  pack_lorab<<<128, 256, 0, stream>>>(up_B_w,   B2w, DIM_D, K2, DIM_F, 32768);

  // router (+ x -> packed bf16 into xbw cols 0..1023)
  router_kernel<<<M_TOK / 4, 256, 0, stream>>>(x, router_w, router_b, routing,
                                               ec, idxp, xbw);
  // LoRA-A down: xbw packed cols 1024..1279 = mask(0.5*(x.dA^T + b))
  lora_a_gemm<DIM_D, K1, K1, DIM_D>
      <<<dim3(2, M_TOK / 128), 256, 0, stream>>>(xbw, dAb, down_A_b, idxp, xbw);
  // GEMM1: aw packed cols 0..4095 = gelu(xbw . B1w^T + fc1_b + 0.5*dB_b[e])
  gemm256<K1, DIM_F, K2, 1>
      <<<dim3(DIM_F / 256, M_TOK / 256), 512, 0, stream>>>(
          xbw, B1w, down_B_b, fc1_b, idxp, aw);
  // LoRA-A up: aw packed cols 4096..4351 = mask(0.5*(a.uA^T + b))
  lora_a_gemm<DIM_F, K2, K2, DIM_F>
      <<<dim3(2, M_TOK / 128), 256, 0, stream>>>(aw, uAb, up_A_b, idxp, aw);
  // GEMM2: out = aw . B2w^T + fc2_b + 0.5*uB_b[e]  (fp32 row-major)
  gemm256<K2, DIM_D, DIM_D, 0>
      <<<dim3(DIM_D / 256, M_TOK / 256), 512, 0, stream>>>(
          aw, B2w, up_B_b, fc2_b, idxp, out);
}

// Round 5
// 648.595 us; speedup vs baseline: 1.1784x; 1.0189x over previous
//
#include <hip/hip_runtime.h>
#include <hip/hip_bf16.h>
#include <math.h>

// B=16,S=1024 -> M=16384 tokens; D=1024, F=4096, E=8, R=32, SCALING=0.5
// Big GEMMs: 256x256 tile, BK=64, 8 waves. PACKED operand layout: each
// 256-row x 32-col half-tile is a contiguous 16KB block with the bank
// swizzle baked in: short_off(r,c) = r*32 + (c ^ ((r&8)<<1)). Staging is a
// verbatim contiguous copy (1KiB per global_load_lds instruction).
// K-loop schedule: m201 idiom - reads+stage issued PRE-barrier,
// __builtin_amdgcn_s_barrier() (no implicit drain), explicit
// s_waitcnt lgkmcnt(0) POST-barrier before MFMA (reads overlap barrier
// convergence and other waves' MFMA). Counted vmcnt(4) at phases 2/4,
// never 0 mid-loop. LoRA-B folded into K: GEMM1 [M,1280]x[4096,1280]^T,
// GEMM2 [M,4352]x[1024,4352]^T.

#define M_TOK 16384
#define DIM_D 1024
#define DIM_F 4096
#define NEXP 8
#define RANK 32
#define NER 256   // NEXP*RANK
#define K1 1280   // DIM_D + NER
#define K2 4352   // DIM_F + NER

typedef __attribute__((ext_vector_type(8))) short bf16x8;
typedef __attribute__((ext_vector_type(4))) short sh4;
typedef __attribute__((ext_vector_type(4))) float f32x4;

__device__ inline short f2bs(float x) {
  __hip_bfloat16 h = __float2bfloat16(x);
  return *reinterpret_cast<short*>(&h);
}

__device__ inline void async16(const void* g, void* l) {
  __builtin_amdgcn_global_load_lds(
      (__attribute__((address_space(1))) void*)(g),
      (__attribute__((address_space(3))) void*)(l), 16, 0, 0);
}

// packed-layout helpers: blk = half-tile index, off = swizzled in-block offset
// packed element (row, k) of a [rows, KP] matrix:
//   blk  = (row>>8)*(KP>>5) + (k>>5)
//   off  = (row&255)*32 + ((k&31) ^ ((row&8)<<1))        [shorts]
__device__ inline size_t pk_blk(int row, int k, int KP) {
  return (size_t)(row >> 8) * (KP >> 5) + (k >> 5);
}
__device__ inline int pk_off(int row, int k) {
  return (row & 255) * 32 + ((k & 31) ^ ((row & 8) << 1));
}

// ---------- fp32 [rows,C] -> packed bf16 (KP-pitch), 8 cols/thread ----------
__global__ __launch_bounds__(256) void convert_packed(
    const float* __restrict__ in, short* __restrict__ out,
    int c8, int KP, int n8)
{
  const int i = blockIdx.x * 256 + threadIdx.x;
  if (i >= n8) return;
  const int row = i / c8;
  const int k = (i % c8) * 8;
  const float4* p = (const float4*)(in + (size_t)row * (c8 * 8) + k);
  float4 u = p[0], v = p[1];
  bf16x8 r;
  r[0] = f2bs(u.x); r[1] = f2bs(u.y); r[2] = f2bs(u.z); r[3] = f2bs(u.w);
  r[4] = f2bs(v.x); r[5] = f2bs(v.y); r[6] = f2bs(v.z); r[7] = f2bs(v.w);
  *(bf16x8*)(out + pk_blk(row, k, KP) * 8192 + pk_off(row, k)) = r;
}

// ---------- LoRA-B [E,Nn,R] fp32 -> packed bf16 at k = ooff+e*32 ----------
__global__ __launch_bounds__(256) void pack_lorab(
    const float* __restrict__ in, short* __restrict__ out,
    int Nn, int KP, int ooff, int n8)
{
  const int i = blockIdx.x * 256 + threadIdx.x;
  if (i >= n8) return;
  const int e = i / (Nn * 4);
  const int rem = i % (Nn * 4);
  const int n = rem >> 2;
  const int r8 = (rem & 3) * 8;
  const int k = ooff + e * RANK + r8;
  const float4* p = (const float4*)(in + ((size_t)e * Nn + n) * RANK + r8);
  float4 u = p[0], v = p[1];
  bf16x8 r;
  r[0] = f2bs(u.x); r[1] = f2bs(u.y); r[2] = f2bs(u.z); r[3] = f2bs(u.w);
  r[4] = f2bs(v.x); r[5] = f2bs(v.y); r[6] = f2bs(v.z); r[7] = f2bs(v.w);
  *(bf16x8*)(out + pk_blk(n, k, KP) * 8192 + pk_off(n, k)) = r;
}

// ---------- router (one wave per token) + fused x->bf16 into packed xbw ----
__global__ __launch_bounds__(256) void router_kernel(
    const float* __restrict__ X,     // [M, D]
    const float* __restrict__ RW,    // [E, D]
    const float* __restrict__ RB,    // [E]
    float* __restrict__ routing_out, // [M, E]
    float* __restrict__ ec_out,      // [M, E]
    int* __restrict__ idx_out,       // [M]
    short* __restrict__ XB)          // packed [M, K1] bf16, cols 0..1023
{
  const int wave = threadIdx.x >> 6;
  const int lane = threadIdx.x & 63;
  const int t = blockIdx.x * 4 + wave;

  const float4* xp = (const float4*)(X + (size_t)t * DIM_D);
  float4 xv[4];
#pragma unroll
  for (int i = 0; i < 4; ++i) xv[i] = xp[lane + 64 * i];

  // fused bf16 conversion of x into packed A buffer (4-short runs stay
  // contiguous under the 16-short XOR since k0 is 4-aligned within 16)
#pragma unroll
  for (int i = 0; i < 4; ++i) {
    sh4 o;
    o[0] = f2bs(xv[i].x); o[1] = f2bs(xv[i].y);
    o[2] = f2bs(xv[i].z); o[3] = f2bs(xv[i].w);
    const int k0 = (lane + 64 * i) * 4;
    *(sh4*)&XB[pk_blk(t, k0, K1) * 8192 + pk_off(t, k0)] = o;
  }

  float logit[NEXP];
#pragma unroll
  for (int e = 0; e < NEXP; ++e) {
    const float4* wp = (const float4*)(RW + (size_t)e * DIM_D);
    double p = 0.0;
#pragma unroll
    for (int i = 0; i < 4; ++i) {
      float4 w = wp[lane + 64 * i];
      p += (double)xv[i].x * w.x + (double)xv[i].y * w.y +
           (double)xv[i].z * w.z + (double)xv[i].w * w.w;
    }
#pragma unroll
    for (int off = 32; off > 0; off >>= 1) p += __shfl_xor(p, off);
    logit[e] = (float)p + RB[e];
  }
  float m = logit[0];
  int am = 0;
#pragma unroll
  for (int e = 1; e < NEXP; ++e)
    if (logit[e] > m) { m = logit[e]; am = e; }
  float pr[NEXP], s = 0.f;
#pragma unroll
  for (int e = 0; e < NEXP; ++e) { pr[e] = expf(logit[e] - m); s += pr[e]; }
  const float inv = 1.f / s;
  if (lane < NEXP) {
    float r = pr[lane] * inv;
    routing_out[(size_t)t * NEXP + lane] = r;
    float y = (lane == am) ? 1.f : 0.f;
    ec_out[(size_t)t * NEXP + lane] = (y - r) + r;
  }
  if (lane == 0) idx_out[t] = am;
}

// ---------- LoRA-A GEMM (N=256), 128x128 tile, packed in/out ----------
// out packed col (OOFF+gc) = bf16( gc>>5==idx[t] ? 0.5*(acc + A_b[gc]) : 0 )
template <int KM, int LDA, int OPK, int OOFF>
__global__ __launch_bounds__(256, 2) void lora_a_gemm(
    const short* __restrict__ A, const short* __restrict__ Bm,
    const float* __restrict__ bias, const int* __restrict__ idx,
    short* __restrict__ out)
{
  __shared__ __align__(16) short As[128 * 32];
  __shared__ __align__(16) short Bs[128 * 32];

  const int tid = threadIdx.x;
  const int m0 = blockIdx.y * 128;
  const int n0 = blockIdx.x * 128;
  const int lane = tid & 63;
  const int wv = tid >> 6;
  const int quad = lane >> 4;
  const int lrow = lane & 15;
  const int wr = wv >> 1;
  const int wc = wv & 1;
  const int swz = (quad * 8) ^ ((lrow & 8) << 1);

  f32x4 acc[4][4];
#pragma unroll
  for (int i = 0; i < 4; ++i)
#pragma unroll
    for (int j = 0; j < 4; ++j) acc[i][j] = (f32x4){0.f, 0.f, 0.f, 0.f};

  const short* Ab = A + ((size_t)(m0 >> 8) * (LDA >> 5)) * 8192 +
                    (size_t)(m0 & 255) * 32;
  const short* Bb = Bm + ((size_t)(n0 >> 8) * (KM >> 5)) * 8192 +
                    (size_t)(n0 & 255) * 32;

  for (int it = 0; it < KM / 32; ++it) {
    const short* a0 = Ab + (size_t)it * 8192 + tid * 8;
    const short* b0 = Bb + (size_t)it * 8192 + tid * 8;
    async16(a0, &As[tid * 8]);
    async16(a0 + 2048, &As[tid * 8 + 2048]);
    async16(b0, &Bs[tid * 8]);
    async16(b0 + 2048, &Bs[tid * 8 + 2048]);
    __syncthreads();

    bf16x8 af[4], bfv[4];
#pragma unroll
    for (int i = 0; i < 4; ++i)
      af[i] = *(const bf16x8*)&As[(wr * 64 + i * 16 + lrow) * 32 + swz];
#pragma unroll
    for (int j = 0; j < 4; ++j)
      bfv[j] = *(const bf16x8*)&Bs[(wc * 64 + j * 16 + lrow) * 32 + swz];
#pragma unroll
    for (int i = 0; i < 4; ++i)
#pragma unroll
      for (int j = 0; j < 4; ++j)
        acc[i][j] = __builtin_amdgcn_mfma_f32_16x16x32_bf16(af[i], bfv[j],
                                                            acc[i][j], 0, 0, 0);
    __syncthreads();
  }

  float cb[4];
#pragma unroll
  for (int j = 0; j < 4; ++j) cb[j] = bias[n0 + wc * 64 + j * 16 + lrow];

#pragma unroll
  for (int i = 0; i < 4; ++i) {
#pragma unroll
    for (int reg = 0; reg < 4; ++reg) {
      const int t = m0 + wr * 64 + i * 16 + quad * 4 + reg;
      const int e = idx[t];
#pragma unroll
      for (int j = 0; j < 4; ++j) {
        const int gc = n0 + wc * 64 + j * 16 + lrow;
        float v = ((gc >> 5) == e) ? 0.5f * (acc[i][j][reg] + cb[j]) : 0.f;
        const int k = OOFF + gc;
        out[pk_blk(t, k, OPK) * 8192 + pk_off(t, k)] = f2bs(v);
      }
    }
  }
}

// ---------- 256x256 GEMM, C = A[M,K] * Bm[N,K]^T ----------
// Packed operands; staging = contiguous 16KB half-tile copies (1KiB/instr).
// m201 phase idiom: {reads+stage issued} -> builtin s_barrier ->
// s_waitcnt lgkmcnt(0) -> setprio(1) MFMA setprio(0) -> builtin s_barrier.
// vmcnt(4) at ends of phases 2 and 4 of each 64-K window (never 0 mid-loop).
// EPI: 1 = gelu(acc+bias+0.5*LB[e]) -> packed bf16 (KP=POUT)
//      0 = acc+bias+0.5*LB[e]       -> fp32 row-major pitch POUT
template <int K, int N, int POUT, int EPI>
__global__ __launch_bounds__(512, 2) void gemm256(
    const short* __restrict__ A, const short* __restrict__ Bm,
    const float* __restrict__ LB, const float* __restrict__ bias,
    const int* __restrict__ idx, void* __restrict__ outv)
{
  static_assert(K % 128 == 0, "K must be multiple of 128");
  __shared__ __align__(16) short lds[65536];  // 2 buf x (A 16K + B 16K) shorts

  const int tid = threadIdx.x;
  const int lane = tid & 63;
  const int wv = tid >> 6;
  const int wr = wv >> 2;   // 0..1
  const int wc = wv & 3;    // 0..3
  const int quad = lane >> 4;
  const int lrow = lane & 15;

  // T1: XCD swizzle (nwg % 8 == 0 for both grids), row-major over N
  const int gx = gridDim.x;
  int id = blockIdx.y * gx + blockIdx.x;
  const int nwg = gx * gridDim.y;
  id = (id & 7) * (nwg >> 3) + (id >> 3);
  const int m0 = (id / gx) * 256;
  const int n0 = (id % gx) * 256;

  const short* Abase = A + (size_t)(m0 >> 8) * (K >> 5) * 8192;
  const short* Bbase = Bm + (size_t)(n0 >> 8) * (K >> 5) * 8192;

  // swizzled read offsets (shorts): row*32 + (quad*8 ^ ((lrow&8)<<1))
  const int swz = (quad * 8) ^ ((lrow & 8) << 1);
  const int arowb = wr * 4096 + lrow * 32 + swz;          // A: + mh*2048 + i*512
  const int browb = 16384 + wc * 2048 + lrow * 32 + swz;  // B: + j*512

  f32x4 acc[8][4];
#pragma unroll
  for (int i = 0; i < 8; ++i)
#pragma unroll
    for (int j = 0; j < 4; ++j) acc[i][j] = (f32x4){0.f, 0.f, 0.f, 0.f};

  bf16x8 af[4], bfv[4];

#define STG(base, t, h, tens, buf)                                           \
  {                                                                          \
    const short* s_ = (base) + (size_t)(2 * (t) + (h)) * 8192 + tid * 8;     \
    short* d_ = &lds[(buf)*32768 + (tens) + (h)*8192 + tid * 8];             \
    async16(s_, d_);                                                         \
    async16(s_ + 4096, d_ + 4096);                                           \
  }
#define RDB(h, buf)                                                          \
  _Pragma("unroll") for (int j = 0; j < 4; ++j)                              \
      bfv[j] = *(const bf16x8*)&lds[(buf)*32768 + (h)*8192 + browb + j * 512];
#define RDA(mh, h, buf)                                                      \
  _Pragma("unroll") for (int i = 0; i < 4; ++i)                              \
      af[i] = *(const bf16x8*)&lds[(buf)*32768 + (h)*8192 + arowb +          \
                                   (mh)*2048 + i * 512];
#define MM(mh)                                                               \
  {                                                                          \
    _Pragma("unroll") for (int i = 0; i < 4; ++i)                            \
    _Pragma("unroll") for (int j = 0; j < 4; ++j)                            \
        acc[(mh)*4 + i][j] = __builtin_amdgcn_mfma_f32_16x16x32_bf16(        \
            af[i], bfv[j], acc[(mh)*4 + i][j], 0, 0, 0);                     \
  }
#define BARR __builtin_amdgcn_s_barrier()
#define LGK0 asm volatile("s_waitcnt lgkmcnt(0)")
#define PRI1 __builtin_amdgcn_s_setprio(1)
#define PRI0 __builtin_amdgcn_s_setprio(0)
#define WV4 asm volatile("s_waitcnt vmcnt(4)")
#define WV0 asm volatile("s_waitcnt vmcnt(0)")
// one 64-K window: compute buf b (tile t), stage tile t+1 into buf nb.
// Ledger (verified): drain@P2 guarantees halves staged 2-3 phases earlier
// (prev window P3/P4 = this tile's h1) landed; drain@P4 guarantees this
// window's P1/P2 stages (next tile's h0) landed before next window P1.
#define TILE(t, b, nb)                                                       \
  RDB(0, b); RDA(0, 0, b); STG(Abase, (t) + 1, 0, 0, nb);                    \
  BARR; LGK0; PRI1; MM(0); PRI0; BARR;                                       \
  RDA(1, 0, b); STG(Bbase, (t) + 1, 0, 16384, nb);                           \
  BARR; LGK0; PRI1; MM(1); PRI0; WV4; BARR;                                  \
  RDB(1, b); RDA(0, 1, b); STG(Abase, (t) + 1, 1, 0, nb);                    \
  BARR; LGK0; PRI1; MM(0); PRI0; BARR;                                       \
  RDA(1, 1, b); STG(Bbase, (t) + 1, 1, 16384, nb);                           \
  BARR; LGK0; PRI1; MM(1); PRI0; WV4; BARR;

  // prologue: stage tile 0 fully into buf 0; h0 must land, h1 may fly
  STG(Abase, 0, 0, 0, 0);
  STG(Bbase, 0, 0, 16384, 0);
  STG(Abase, 0, 1, 0, 0);
  STG(Bbase, 0, 1, 16384, 0);
  WV4; BARR;

  constexpr int NI = K / 128;  // 10 or 34
  for (int it = 0; it < NI - 1; ++it) {
    TILE(2 * it, 0, 1);
    TILE(2 * it + 1, 1, 0);
  }
  TILE(2 * NI - 2, 0, 1);  // stages last tile (2*NI-1) into buf1
  {  // last tile (buf 1), no staging; WV0 before its h1 reads
    RDB(0, 1); RDA(0, 0, 1); BARR; LGK0; PRI1; MM(0); PRI0; BARR;
    RDA(1, 0, 1);            BARR; LGK0; PRI1; MM(1); PRI0; WV0; BARR;
    RDB(1, 1); RDA(0, 1, 1); BARR; LGK0; PRI1; MM(0); PRI0; BARR;
    RDA(1, 1, 1);                  LGK0; PRI1; MM(1); PRI0;
  }
#undef STG
#undef RDB
#undef RDA
#undef MM
#undef BARR
#undef LGK0
#undef PRI1
#undef PRI0
#undef WV4
#undef WV0
#undef TILE

  // epilogue: C row = quad*4+reg, col = lrow (dtype-independent C/D map)
  const int orow0 = m0 + wr * 128;
  const int ocol0 = n0 + wc * 64;
  float cb[4];
#pragma unroll
  for (int j = 0; j < 4; ++j) cb[j] = bias[ocol0 + j * 16 + lrow];

#pragma unroll
  for (int i = 0; i < 8; ++i) {
#pragma unroll
    for (int reg = 0; reg < 4; ++reg) {
      const int t = orow0 + i * 16 + quad * 4 + reg;
      const int e = idx[t];
      const float* lbp = LB + (size_t)e * N;
#pragma unroll
      for (int j = 0; j < 4; ++j) {
        const int gc = ocol0 + j * 16 + lrow;
        float v = acc[i][j][reg] + cb[j] + 0.5f * lbp[gc];
        if (EPI == 1) {
          v = 0.5f * v * (1.0f + erff(v * 0.70710678118654752f));
          ((short*)outv)[pk_blk(t, gc, POUT) * 8192 + pk_off(t, gc)] = f2bs(v);
        } else {
          ((float*)outv)[(size_t)t * POUT + gc] = v;
        }
      }
    }
  }
}

extern "C" void kernel_launch(void* const* d_in, const int* in_sizes, int n_in,
                              void* d_out, int out_size, void* d_ws, size_t ws_size,
                              hipStream_t stream) {
  (void)in_sizes; (void)n_in; (void)out_size; (void)ws_size;
  const float* x        = (const float*)d_in[0];
  const float* router_w = (const float*)d_in[1];
  const float* router_b = (const float*)d_in[2];
  const float* fc1_w    = (const float*)d_in[3];
  const float* fc1_b    = (const float*)d_in[4];
  const float* fc2_w    = (const float*)d_in[5];
  const float* fc2_b    = (const float*)d_in[6];
  const float* down_A_w = (const float*)d_in[7];   // [E,R,D]
  const float* down_A_b = (const float*)d_in[8];   // [E*R]
  const float* down_B_w = (const float*)d_in[9];   // [E,F,R]
  const float* down_B_b = (const float*)d_in[10];  // [E,F]
  const float* up_A_w   = (const float*)d_in[11];  // [E,R,F]
  const float* up_A_b   = (const float*)d_in[12];  // [E*R]
  const float* up_B_w   = (const float*)d_in[13];  // [E,D,R]
  const float* up_B_b   = (const float*)d_in[14];  // [E,D]

  // ws: idx | xbw pk[M,K1] | aw pk[M,K2] | B1w pk[F,K1] | B2w pk[D,K2] | dAb | uAb
  char* ws = (char*)d_ws;
  size_t off = 0;
  int* idxp  = (int*)ws;              off += (size_t)M_TOK * 4;
  short* xbw = (short*)(ws + off);    off += (size_t)M_TOK * K1 * 2;
  short* aw  = (short*)(ws + off);    off += (size_t)M_TOK * K2 * 2;
  short* B1w = (short*)(ws + off);    off += (size_t)DIM_F * K1 * 2;
  short* B2w = (short*)(ws + off);    off += (size_t)DIM_D * K2 * 2;
  short* dAb = (short*)(ws + off);    off += (size_t)NER * DIM_D * 2;
  short* uAb = (short*)(ws + off);    off += (size_t)NER * DIM_F * 2;

  float* out = (float*)d_out;
  float* routing = out + (size_t)M_TOK * DIM_D;
  float* ec = routing + (size_t)M_TOK * NEXP;

  // weight conversions / packing into packed-tile layouts
  convert_packed<<<2048, 256, 0, stream>>>(fc1_w, B1w, 128, K1, 524288);
  convert_packed<<<2048, 256, 0, stream>>>(fc2_w, B2w, 512, K2, 524288);
  convert_packed<<<128,  256, 0, stream>>>(down_A_w, dAb, 128, DIM_D, 32768);
  convert_packed<<<512,  256, 0, stream>>>(up_A_w,   uAb, 512, DIM_F, 131072);
  pack_lorab<<<512, 256, 0, stream>>>(down_B_w, B1w, DIM_F, K1, DIM_D, 131072);
  pack_lorab<<<128, 256, 0, stream>>>(up_B_w,   B2w, DIM_D, K2, DIM_F, 32768);

  // router (+ x -> packed bf16 into xbw cols 0..1023)
  router_kernel<<<M_TOK / 4, 256, 0, stream>>>(x, router_w, router_b, routing,
                                               ec, idxp, xbw);
  // LoRA-A down: xbw packed cols 1024..1279 = mask(0.5*(x.dA^T + b))
  lora_a_gemm<DIM_D, K1, K1, DIM_D>
      <<<dim3(2, M_TOK / 128), 256, 0, stream>>>(xbw, dAb, down_A_b, idxp, xbw);
  // GEMM1: aw packed cols 0..4095 = gelu(xbw . B1w^T + fc1_b + 0.5*dB_b[e])
  gemm256<K1, DIM_F, K2, 1>
      <<<dim3(DIM_F / 256, M_TOK / 256), 512, 0, stream>>>(
          xbw, B1w, down_B_b, fc1_b, idxp, aw);
  // LoRA-A up: aw packed cols 4096..4351 = mask(0.5*(a.uA^T + b))
  lora_a_gemm<DIM_F, K2, K2, DIM_F>
      <<<dim3(2, M_TOK / 128), 256, 0, stream>>>(aw, uAb, up_A_b, idxp, aw);
  // GEMM2: out = aw . B2w^T + fc2_b + 0.5*uB_b[e]  (fp32 row-major)
  gemm256<K2, DIM_D, DIM_D, 0>
      <<<dim3(DIM_D / 256, M_TOK / 256), 512, 0, stream>>>(
          aw, B2w, up_B_b, fc2_b, idxp, out);
}